// Round 10
// baseline (258.142 us; speedup 1.0000x reference)
//
#include <hip/hip_runtime.h>

// CapsNet dynamic routing — per-batch blocks, 2 launches.
// R10 = R9 + __attribute__((amdgpu_waves_per_eu(4,4))): R7-R9 all compiled
// with a 64-VGPR cap (backend occupancy heuristic targeting 8 waves/EU),
// which force-spilled the 64 VGPRs of x-fragments to scratch (WRITE_SIZE
// 124 MiB = 262144 threads x 496 B). launch_bounds' 2nd arg did not move
// the cap; amdgpu_waves_per_eu(4,4) is the allocator-binding knob ->
// 128-VGPR budget. 1024-thr block needs exactly 4 waves/EU; LDS already
// limits to 1 block/CU, so nothing is traded away.
//   init: x converted fp32->fp16 via two LDS half-slabs into per-lane MFMA
//         B-fragments: yfrag[8] (x16[c][i]) and dfrag[8] (xT[i][c]).
//   3 iterations, all on-chip except W (streamed from per-XCD L2):
//     delta = u@xT (MFMA) ; b += delta+vb (registers)
//     softmax over j (register shfl) ; c -> LDS ; y = c@x (MFMA) -> ysh
//     s[j,d] = dot8(Wp, ysh) ; v = squash(s) ; u[j,c] = dot8(Wd, v) -> ush

#define BSZ 256
#define CDIM 256
#define IDIM 256
#define JDIM 32
#define DDIM 64

typedef _Float16 f16x8 __attribute__((ext_vector_type(8)));
typedef _Float16 f16x4 __attribute__((ext_vector_type(4)));
typedef float f32x4 __attribute__((ext_vector_type(4)));

__device__ __forceinline__ float dot8(f16x8 a, f16x8 b, float acc) {
#if __has_builtin(__builtin_amdgcn_fdot2)
  acc = __builtin_amdgcn_fdot2(__builtin_shufflevector(a, a, 0, 1),
                               __builtin_shufflevector(b, b, 0, 1), acc, false);
  acc = __builtin_amdgcn_fdot2(__builtin_shufflevector(a, a, 2, 3),
                               __builtin_shufflevector(b, b, 2, 3), acc, false);
  acc = __builtin_amdgcn_fdot2(__builtin_shufflevector(a, a, 4, 5),
                               __builtin_shufflevector(b, b, 4, 5), acc, false);
  acc = __builtin_amdgcn_fdot2(__builtin_shufflevector(a, a, 6, 7),
                               __builtin_shufflevector(b, b, 6, 7), acc, false);
#else
  #pragma unroll
  for (int e = 0; e < 8; ++e) acc += (float)a[e] * (float)b[e];
#endif
  return acc;
}

// ---------------------------------------------------------------------------
// prep_w: grid 32 (block = j), block 256. Stage W_j in LDS, emit both packs.
// ---------------------------------------------------------------------------
__global__ __launch_bounds__(256) void prep_w(
    const float* __restrict__ W,   // [JDIM*DDIM][CDIM]
    _Float16* __restrict__ Wp,     // f16x8 [(j*32+g)*64+d] over c=8g..8g+7
    _Float16* __restrict__ Wd)     // f16x8 [(j*8+h)*256+c] over d=8h..8h+7
{
  __shared__ __align__(16) float Wsh[64 * 260];
  const int j = blockIdx.x, t = threadIdx.x;

  #pragma unroll
  for (int k = 0; k < 16; ++k) {
    const int q = k * 256 + t;
    const int row = q >> 6, c4 = (q & 63) * 4;
    *reinterpret_cast<f32x4*>(&Wsh[row * 260 + c4]) =
        *reinterpret_cast<const f32x4*>(&W[((size_t)j * 64 + row) * 256 + c4]);
  }
  __syncthreads();

  {
    const int d = t & 63;
    f16x8* out = reinterpret_cast<f16x8*>(Wp) + (size_t)j * 2048;
    #pragma unroll
    for (int k = 0; k < 8; ++k) {
      const int g = (t >> 6) + 4 * k;
      f32x4 a = *reinterpret_cast<const f32x4*>(&Wsh[d * 260 + 8 * g]);
      f32x4 bq = *reinterpret_cast<const f32x4*>(&Wsh[d * 260 + 8 * g + 4]);
      f16x8 h;
      h[0] = (_Float16)a[0]; h[1] = (_Float16)a[1];
      h[2] = (_Float16)a[2]; h[3] = (_Float16)a[3];
      h[4] = (_Float16)bq[0]; h[5] = (_Float16)bq[1];
      h[6] = (_Float16)bq[2]; h[7] = (_Float16)bq[3];
      out[g * 64 + d] = h;
    }
  }
  {
    const int c = t;
    f16x8* out = reinterpret_cast<f16x8*>(Wd) + (size_t)j * 2048;
    #pragma unroll
    for (int h = 0; h < 8; ++h) {
      f16x8 hh;
      #pragma unroll
      for (int e = 0; e < 8; ++e) hh[e] = (_Float16)Wsh[(8 * h + e) * 260 + c];
      out[h * 256 + c] = hh;
    }
  }
}

// ---------------------------------------------------------------------------
__global__ __launch_bounds__(1024)
__attribute__((amdgpu_waves_per_eu(4, 4)))
void caps_routing(
    const float* __restrict__ x,       // [BSZ][CDIM][IDIM] fp32
    const float* __restrict__ bias,    // [JDIM*DDIM] fp32
    const float* __restrict__ b_init,  // [BSZ][JDIM][IDIM] fp32
    const _Float16* __restrict__ Wp,
    const _Float16* __restrict__ Wd,
    float* __restrict__ vout)          // [BSZ][JDIM][DDIM]
{
  // LDS arena: init uses slabR (67584 B) + slabT (69632 B) = 137216 B.
  // steady state uses cs/ush/ysh/vsh/csum/vbs = 55 KB (time-disjoint).
  __shared__ __align__(16) char arena[137216];
  _Float16* slabR = reinterpret_cast<_Float16*>(arena);            // [128][264]
  _Float16* slabT = reinterpret_cast<_Float16*>(arena + 67584);    // [256][136]
  _Float16* cs    = reinterpret_cast<_Float16*>(arena);            // [32][264]
  _Float16* ush   = reinterpret_cast<_Float16*>(arena + 16896);    // [32][264]
  _Float16* ysh   = reinterpret_cast<_Float16*>(arena + 33792);    // [32][264]
  _Float16* vsh16 = reinterpret_cast<_Float16*>(arena + 50688);    // [32][64]
  float* csumsh   = reinterpret_cast<float*>(arena + 54784);       // [32]
  float* vbs      = reinterpret_cast<float*>(arena + 54912);       // [32]

  const int b = blockIdx.x, t = threadIdx.x;
  const int w = t >> 6, lane = t & 63, l15 = lane & 15, quad = lane >> 4;

  f16x8 yfrag[8];   // x16[c = w*16+l15][kk*32+quad*8 ..+8]
  f16x8 dfrag[8];   // xT [i = w*16+l15][kk*32+quad*8 ..+8]

  // ---- init: convert x through two LDS half-slabs, load frags ----
  // Fully unrolled so all frag indices are compile-time constants.
  #pragma unroll
  for (int h = 0; h < 2; ++h) {
    #pragma unroll
    for (int q = 0; q < 2; ++q) {
      const int idx = q * 1024 + t;
      const int c4 = (idx >> 6) * 4;      // 0..124 (local c in half)
      const int i4 = (idx & 63) * 4;      // 0..252
      const float* src = x + (size_t)b * 65536 + (size_t)(h * 128 + c4) * 256 + i4;
      f32x4 v[4];
      #pragma unroll
      for (int s = 0; s < 4; ++s)
        v[s] = *reinterpret_cast<const f32x4*>(src + s * 256);
      #pragma unroll
      for (int s = 0; s < 4; ++s) {
        f16x4 hh;
        hh[0] = (_Float16)v[s][0]; hh[1] = (_Float16)v[s][1];
        hh[2] = (_Float16)v[s][2]; hh[3] = (_Float16)v[s][3];
        *reinterpret_cast<f16x4*>(&slabR[(c4 + s) * 264 + i4]) = hh;
      }
      #pragma unroll
      for (int m = 0; m < 4; ++m) {
        f16x4 hh;
        hh[0] = (_Float16)v[0][m]; hh[1] = (_Float16)v[1][m];
        hh[2] = (_Float16)v[2][m]; hh[3] = (_Float16)v[3][m];
        *reinterpret_cast<f16x4*>(&slabT[(i4 + m) * 136 + c4]) = hh;
      }
    }
    __syncthreads();
    if ((w >> 3) == h) {
      const int cloc = (w & 7) * 16 + l15;
      #pragma unroll
      for (int m = 0; m < 8; ++m)
        yfrag[m] = *reinterpret_cast<const f16x8*>(
            &slabR[cloc * 264 + quad * 8 + 32 * m]);
    }
    {
      const int ii = w * 16 + l15;
      #pragma unroll
      for (int kk = 0; kk < 4; ++kk)
        dfrag[h * 4 + kk] = *reinterpret_cast<const f16x8*>(
            &slabT[ii * 136 + kk * 32 + quad * 8]);
    }
    __syncthreads();
  }

  // ---- b -> registers, D-layout: j = mt*16+quad*4+rr, ii = w*16+l15 ----
  float breg[2][4];
  {
    const float* bp = b_init + (size_t)b * 8192;
    #pragma unroll
    for (int mt = 0; mt < 2; ++mt)
      #pragma unroll
      for (int rr = 0; rr < 4; ++rr)
        breg[mt][rr] = bp[(mt * 16 + quad * 4 + rr) * 256 + w * 16 + l15];
  }
  // per-wave bias cache (wave w owns j = w, w+16)
  const float bv0 = bias[w * 64 + lane];
  const float bv1 = bias[(w + 16) * 64 + lane];

  const f16x8* WpB = reinterpret_cast<const f16x8*>(Wp);
  const f16x8* WdB = reinterpret_cast<const f16x8*>(Wd);

  for (int r = 0; r < 3; ++r) {
    if (r) {
      // ---- delta[j,ii] = sum_c u[j,c] * xT[ii,c]  (B from dfrag regs) ----
      f32x4 acc0 = (f32x4){0.f, 0.f, 0.f, 0.f};
      f32x4 acc1 = (f32x4){0.f, 0.f, 0.f, 0.f};
      #pragma unroll
      for (int kk = 0; kk < 8; ++kk) {
        const int ko = kk * 32 + quad * 8;
        f16x8 a0 = *reinterpret_cast<const f16x8*>(&ush[l15 * 264 + ko]);
        f16x8 a1 = *reinterpret_cast<const f16x8*>(&ush[(16 + l15) * 264 + ko]);
        acc0 = __builtin_amdgcn_mfma_f32_16x16x32_f16(a0, dfrag[kk], acc0, 0, 0, 0);
        acc1 = __builtin_amdgcn_mfma_f32_16x16x32_f16(a1, dfrag[kk], acc1, 0, 0, 0);
      }
      #pragma unroll
      for (int rr = 0; rr < 4; ++rr) {
        breg[0][rr] += acc0[rr] + vbs[quad * 4 + rr];
        breg[1][rr] += acc1[rr] + vbs[16 + quad * 4 + rr];
      }
    }

    if (t < 32) csumsh[t] = 0.f;

    // ---- softmax over j (registers + shfl across quads) ----
    float cc[2][4];
    {
      float m = breg[0][0];
      #pragma unroll
      for (int mt = 0; mt < 2; ++mt)
        #pragma unroll
        for (int rr = 0; rr < 4; ++rr) m = fmaxf(m, breg[mt][rr]);
      m = fmaxf(m, __shfl_xor(m, 16));
      m = fmaxf(m, __shfl_xor(m, 32));
      float s = 0.f;
      #pragma unroll
      for (int mt = 0; mt < 2; ++mt)
        #pragma unroll
        for (int rr = 0; rr < 4; ++rr) {
          float e = __expf(breg[mt][rr] - m);
          cc[mt][rr] = e; s += e;
        }
      s += __shfl_xor(s, 16);
      s += __shfl_xor(s, 32);
      const float rinv = 1.f / s;
      const int ii = w * 16 + l15;
      #pragma unroll
      for (int mt = 0; mt < 2; ++mt)
        #pragma unroll
        for (int rr = 0; rr < 4; ++rr) {
          const float cv = cc[mt][rr] * rinv;
          cc[mt][rr] = cv;
          cs[(mt * 16 + quad * 4 + rr) * 264 + ii] = (_Float16)cv;
        }
    }
    __syncthreads();  // cs visible, csumsh zeroed

    // ---- csum[j] atomics ----
    #pragma unroll
    for (int mt = 0; mt < 2; ++mt)
      #pragma unroll
      for (int rr = 0; rr < 4; ++rr) {
        float pj = cc[mt][rr];
        pj += __shfl_xor(pj, 1);
        pj += __shfl_xor(pj, 2);
        pj += __shfl_xor(pj, 4);
        pj += __shfl_xor(pj, 8);
        if (l15 == 0) atomicAdd(&csumsh[mt * 16 + quad * 4 + rr], pj);
      }

    // ---- y[j,c] = sum_i c[j,i] * x16[c,i]  (B from yfrag regs) ----
    {
      f32x4 acy0 = (f32x4){0.f, 0.f, 0.f, 0.f};
      f32x4 acy1 = (f32x4){0.f, 0.f, 0.f, 0.f};
      #pragma unroll
      for (int kk = 0; kk < 8; ++kk) {
        const int ko = kk * 32 + quad * 8;
        f16x8 a0 = *reinterpret_cast<const f16x8*>(&cs[l15 * 264 + ko]);
        f16x8 a1 = *reinterpret_cast<const f16x8*>(&cs[(16 + l15) * 264 + ko]);
        acy0 = __builtin_amdgcn_mfma_f32_16x16x32_f16(a0, yfrag[kk], acy0, 0, 0, 0);
        acy1 = __builtin_amdgcn_mfma_f32_16x16x32_f16(a1, yfrag[kk], acy1, 0, 0, 0);
      }
      const int cp = w * 16 + l15;
      #pragma unroll
      for (int rr = 0; rr < 4; ++rr) {
        ysh[(quad * 4 + rr) * 264 + cp] = (_Float16)acy0[rr];
        ysh[(16 + quad * 4 + rr) * 264 + cp] = (_Float16)acy1[rr];
      }
    }
    __syncthreads();  // ysh + csumsh complete; ush reads (delta) done

    // ---- per-j s / squash / u (wave w owns j = w, w+16) ----
    #pragma unroll
    for (int jq = 0; jq < 2; ++jq) {
      const int jj = w + jq * 16;
      const float biasv = jq ? bv1 : bv0;
      const f16x8* wrow = WpB + (size_t)jj * 2048 + lane;   // + g*64
      const _Float16* yr = &ysh[jj * 264];
      float sacc = 0.f;
      #pragma unroll 4
      for (int g = 0; g < 32; ++g)
        sacc = dot8(wrow[g * 64], *reinterpret_cast<const f16x8*>(&yr[g * 8]), sacc);
      sacc += biasv * csumsh[jj];

      float n2 = sacc * sacc;
      n2 += __shfl_xor(n2, 1);
      n2 += __shfl_xor(n2, 2);
      n2 += __shfl_xor(n2, 4);
      n2 += __shfl_xor(n2, 8);
      n2 += __shfl_xor(n2, 16);
      n2 += __shfl_xor(n2, 32);
      const float sc = sqrtf(n2) / (1.f + n2);
      const float vv = sacc * sc;

      if (r == 2) {
        vout[((size_t)b * 32 + jj) * 64 + lane] = vv;
      } else {
        vsh16[jj * 64 + lane] = (_Float16)vv;
        float vbp = vv * biasv;
        vbp += __shfl_xor(vbp, 1);
        vbp += __shfl_xor(vbp, 2);
        vbp += __shfl_xor(vbp, 4);
        vbp += __shfl_xor(vbp, 8);
        vbp += __shfl_xor(vbp, 16);
        vbp += __shfl_xor(vbp, 32);
        if (lane == 0) vbs[jj] = vbp;

        // u[jj,c] = sum_d v[jj,d] * W[jj,d,c]   (lane = c base)
        float ua[4] = {0.f, 0.f, 0.f, 0.f};
        const f16x8* wd = WdB + (size_t)jj * 2048;
        #pragma unroll
        for (int h = 0; h < 8; ++h) {
          f16x8 vvv = *reinterpret_cast<const f16x8*>(&vsh16[jj * 64 + h * 8]);
          #pragma unroll
          for (int k = 0; k < 4; ++k)
            ua[k] = dot8(wd[h * 256 + lane + 64 * k], vvv, ua[k]);
        }
        #pragma unroll
        for (int k = 0; k < 4; ++k)
          ush[jj * 264 + lane + 64 * k] = (_Float16)ua[k];
      }
    }
    if (r < 2) __syncthreads();  // ush + vbs visible; cs/ysh reusable
  }
}

// ---------------------------------------------------------------------------
extern "C" void kernel_launch(void* const* d_in, const int* in_sizes, int n_in,
                              void* d_out, int out_size, void* d_ws, size_t ws_size,
                              hipStream_t stream) {
  (void)in_sizes; (void)n_in; (void)out_size; (void)ws_size;
  const float* x      = (const float*)d_in[0];
  const float* W      = (const float*)d_in[1];
  const float* bias   = (const float*)d_in[2];
  const float* b_init = (const float*)d_in[3];
  char* ws = (char*)d_ws;

  _Float16* Wp = (_Float16*)(ws);                 // 1 MiB
  _Float16* Wd = (_Float16*)(ws + (1u << 20));    // 1 MiB
  float* vout  = (float*)d_out;

  prep_w<<<32, 256, 0, stream>>>(W, Wp, Wd);
  caps_routing<<<BSZ, 1024, 0, stream>>>(x, bias, b_init, Wp, Wd, vout);
}

// Round 11
// 193.182 us; speedup vs baseline: 1.3363x; 1.3363x over previous
//
#include <hip/hip_runtime.h>

// CapsNet dynamic routing — split-phase structure, 8 launches (in-graph
// launches are ~free; measured fixed overhead dominates). pred never formed.
//   prep_x: x fp32 -> x16[b][c][i], xT16[b][i][c] fp16 (register 4x4 transpose)
//   prep_w: W fp32 -> W16[j][d][c], WT16[j][c][d] fp16
//   k31 (block=batch, 1024 thr): [delta = u@xT MFMA, b += delta+vb, b roundtrip
//        via global in D-layout] -> softmax(regs+shfl) -> y = c@x MFMA -> y16
//   k2  (block=(j, 32 batches), 512 thr): s = y@W16^T MFMA + bias*csum ;
//        v = squash ; u = v@WT16^T MFMA -> u16   (W read ONCE per 32 batches
//        from L2 -> total W traffic 48 MB vs 1.5 GB in the per-batch design)
// No register-resident x fragments (R7-R10's 124-MB scratch spill: allocator
// caps this kernel shape at 64 arch VGPRs regardless of launch_bounds /
// amdgpu_waves_per_eu).

#define BSZ 256
#define CDIM 256
#define IDIM 256
#define JDIM 32
#define DDIM 64

typedef _Float16 f16x8 __attribute__((ext_vector_type(8)));
typedef _Float16 f16x4 __attribute__((ext_vector_type(4)));
typedef float f32x4 __attribute__((ext_vector_type(4)));

// ---------------------------------------------------------------------------
// prep_x: grid (BSZ, 8), block 256. Register 4x4 transpose, x read once.
// ---------------------------------------------------------------------------
__global__ __launch_bounds__(256) void prep_x(
    const float* __restrict__ x,
    _Float16* __restrict__ x16,
    _Float16* __restrict__ xT16)
{
  const int b = blockIdx.x;
  const int c0 = blockIdx.y * 32;
  const int t = threadIdx.x;
  const float* xb = x + (size_t)b * 65536;
  _Float16* x16b = x16 + (size_t)b * 65536;
  _Float16* xTb  = xT16 + (size_t)b * 65536;

  #pragma unroll
  for (int q = 0; q < 2; ++q) {
    const int tile = q * 256 + t;            // 0..511
    const int c4 = (tile & 7) * 4;           // 0..28
    const int i4 = (tile >> 3) * 4;          // 0..252
    f32x4 v[4];
    #pragma unroll
    for (int s = 0; s < 4; ++s)
      v[s] = *reinterpret_cast<const f32x4*>(&xb[(c0 + c4 + s) * 256 + i4]);
    #pragma unroll
    for (int s = 0; s < 4; ++s) {
      f16x4 h;
      h[0] = (_Float16)v[s][0]; h[1] = (_Float16)v[s][1];
      h[2] = (_Float16)v[s][2]; h[3] = (_Float16)v[s][3];
      *reinterpret_cast<f16x4*>(&x16b[(c0 + c4 + s) * 256 + i4]) = h;
    }
    #pragma unroll
    for (int m = 0; m < 4; ++m) {
      f16x4 h;
      h[0] = (_Float16)v[0][m]; h[1] = (_Float16)v[1][m];
      h[2] = (_Float16)v[2][m]; h[3] = (_Float16)v[3][m];
      *reinterpret_cast<f16x4*>(&xTb[(i4 + m) * 256 + c0 + c4]) = h;
    }
  }
}

// ---------------------------------------------------------------------------
// prep_w: grid 32 (block=j), block 256.
// ---------------------------------------------------------------------------
__global__ __launch_bounds__(256) void prep_w(
    const float* __restrict__ W,     // [JDIM*DDIM][CDIM]
    _Float16* __restrict__ W16,      // [j][d][c]
    _Float16* __restrict__ WT16)     // [j][c][d]
{
  __shared__ __align__(16) float Wsh[64 * 260];
  const int j = blockIdx.x, t = threadIdx.x;

  #pragma unroll
  for (int k = 0; k < 16; ++k) {
    const int q = k * 256 + t;
    const int row = q >> 6, c4 = (q & 63) * 4;
    *reinterpret_cast<f32x4*>(&Wsh[row * 260 + c4]) =
        *reinterpret_cast<const f32x4*>(&W[((size_t)j * 64 + row) * 256 + c4]);
  }
  __syncthreads();

  // W16 rows (straight cvt)
  #pragma unroll
  for (int k = 0; k < 16; ++k) {
    const int q = k * 256 + t;
    const int row = q >> 6, c4 = (q & 63) * 4;
    f32x4 wv = *reinterpret_cast<const f32x4*>(&Wsh[row * 260 + c4]);
    f16x4 h;
    h[0] = (_Float16)wv[0]; h[1] = (_Float16)wv[1];
    h[2] = (_Float16)wv[2]; h[3] = (_Float16)wv[3];
    *reinterpret_cast<f16x4*>(&W16[(size_t)j * 16384 + row * 256 + c4]) = h;
  }
  // WT16: thread t = c, writes 64 d's (8 f16x8 contiguous)
  {
    const int c = t;
    #pragma unroll
    for (int h = 0; h < 8; ++h) {
      f16x8 hh;
      #pragma unroll
      for (int e = 0; e < 8; ++e) hh[e] = (_Float16)Wsh[(8 * h + e) * 260 + c];
      *reinterpret_cast<f16x8*>(&WT16[((size_t)j * 256 + c) * 64 + 8 * h]) = hh;
    }
  }
}

// ---------------------------------------------------------------------------
// k31: grid BSZ, block 1024 (16 waves, wave w owns i/c column w*16+l15).
// mode: 0 = softmax from bsrc only; 1 = delta + store b_new; 2 = delta only.
// ---------------------------------------------------------------------------
__global__ __launch_bounds__(1024) void k31(
    const _Float16* __restrict__ x16,   // [b][c][i]
    const _Float16* __restrict__ xT16,  // [b][i][c]
    const _Float16* __restrict__ u16,   // [b][j][c]
    const float* __restrict__ vb_ws,    // [b][j]
    const float* __restrict__ bsrc,     // [b][j][i]
    float* __restrict__ bdst,           // [b][j][i] (mode 1)
    _Float16* __restrict__ y16,         // [b][j][c]
    float* __restrict__ csum_ws,        // [b][j]
    int mode)
{
  __shared__ __align__(16) _Float16 cs[JDIM * 264];
  __shared__ __align__(16) _Float16 ush[JDIM * 264];
  __shared__ float csumsh[JDIM];
  __shared__ float vbs[JDIM];

  const int b = blockIdx.x, t = threadIdx.x;
  const int w = t >> 6, lane = t & 63, l15 = lane & 15, quad = lane >> 4;
  const int ii = w * 16 + l15;
  const float* bp = bsrc + (size_t)b * 8192;

  float breg[2][4];

  if (mode) {
    // stage u -> LDS (1024 f16x8, one per thread)
    {
      const f16x8* ug = reinterpret_cast<const f16x8*>(u16 + (size_t)b * 8192);
      const int jr = t >> 5, co = (t & 31) * 8;
      *reinterpret_cast<f16x8*>(&ush[jr * 264 + co]) = ug[t];
    }
    if (t < 32) vbs[t] = vb_ws[b * 32 + t];
    __syncthreads();

    const _Float16* xTb = xT16 + (size_t)b * 65536;
    f32x4 acc0 = (f32x4){0.f, 0.f, 0.f, 0.f};
    f32x4 acc1 = (f32x4){0.f, 0.f, 0.f, 0.f};
    #pragma unroll
    for (int kk = 0; kk < 8; ++kk) {
      const int ko = kk * 32 + quad * 8;
      f16x8 a0 = *reinterpret_cast<const f16x8*>(&ush[l15 * 264 + ko]);
      f16x8 a1 = *reinterpret_cast<const f16x8*>(&ush[(16 + l15) * 264 + ko]);
      f16x8 bf = *reinterpret_cast<const f16x8*>(&xTb[ii * 256 + ko]);
      acc0 = __builtin_amdgcn_mfma_f32_16x16x32_f16(a0, bf, acc0, 0, 0, 0);
      acc1 = __builtin_amdgcn_mfma_f32_16x16x32_f16(a1, bf, acc1, 0, 0, 0);
    }
    #pragma unroll
    for (int rr = 0; rr < 4; ++rr) {
      const int j0 = quad * 4 + rr, j1 = 16 + quad * 4 + rr;
      breg[0][rr] = bp[j0 * 256 + ii] + acc0[rr] + vbs[j0];
      breg[1][rr] = bp[j1 * 256 + ii] + acc1[rr] + vbs[j1];
      if (mode == 1) {
        bdst[(size_t)b * 8192 + j0 * 256 + ii] = breg[0][rr];
        bdst[(size_t)b * 8192 + j1 * 256 + ii] = breg[1][rr];
      }
    }
  } else {
    #pragma unroll
    for (int mt = 0; mt < 2; ++mt)
      #pragma unroll
      for (int rr = 0; rr < 4; ++rr)
        breg[mt][rr] = bp[(mt * 16 + quad * 4 + rr) * 256 + ii];
  }

  if (t < 32) csumsh[t] = 0.f;

  // softmax over j (registers + shfl across quads/halves)
  float cc[2][4];
  {
    float m = breg[0][0];
    #pragma unroll
    for (int mt = 0; mt < 2; ++mt)
      #pragma unroll
      for (int rr = 0; rr < 4; ++rr) m = fmaxf(m, breg[mt][rr]);
    m = fmaxf(m, __shfl_xor(m, 16));
    m = fmaxf(m, __shfl_xor(m, 32));
    float s = 0.f;
    #pragma unroll
    for (int mt = 0; mt < 2; ++mt)
      #pragma unroll
      for (int rr = 0; rr < 4; ++rr) {
        float e = __expf(breg[mt][rr] - m);
        cc[mt][rr] = e; s += e;
      }
    s += __shfl_xor(s, 16);
    s += __shfl_xor(s, 32);
    const float rinv = 1.f / s;
    #pragma unroll
    for (int mt = 0; mt < 2; ++mt)
      #pragma unroll
      for (int rr = 0; rr < 4; ++rr) {
        const float cv = cc[mt][rr] * rinv;
        cc[mt][rr] = cv;
        cs[(mt * 16 + quad * 4 + rr) * 264 + ii] = (_Float16)cv;
      }
  }
  __syncthreads();  // cs visible, csumsh zeroed

  // csum[j] atomics
  #pragma unroll
  for (int mt = 0; mt < 2; ++mt)
    #pragma unroll
    for (int rr = 0; rr < 4; ++rr) {
      float pj = cc[mt][rr];
      pj += __shfl_xor(pj, 1);
      pj += __shfl_xor(pj, 2);
      pj += __shfl_xor(pj, 4);
      pj += __shfl_xor(pj, 8);
      if (l15 == 0) atomicAdd(&csumsh[mt * 16 + quad * 4 + rr], pj);
    }

  // y[j,c] = sum_i c[j,i] * x16[c,i]  -> y16 global
  {
    const _Float16* xb = x16 + (size_t)b * 65536;
    f32x4 acy0 = (f32x4){0.f, 0.f, 0.f, 0.f};
    f32x4 acy1 = (f32x4){0.f, 0.f, 0.f, 0.f};
    #pragma unroll
    for (int kk = 0; kk < 8; ++kk) {
      const int ko = kk * 32 + quad * 8;
      f16x8 a0 = *reinterpret_cast<const f16x8*>(&cs[l15 * 264 + ko]);
      f16x8 a1 = *reinterpret_cast<const f16x8*>(&cs[(16 + l15) * 264 + ko]);
      f16x8 bf = *reinterpret_cast<const f16x8*>(&xb[ii * 256 + ko]);
      acy0 = __builtin_amdgcn_mfma_f32_16x16x32_f16(a0, bf, acy0, 0, 0, 0);
      acy1 = __builtin_amdgcn_mfma_f32_16x16x32_f16(a1, bf, acy1, 0, 0, 0);
    }
    _Float16* yb = y16 + (size_t)b * 8192;
    #pragma unroll
    for (int rr = 0; rr < 4; ++rr) {
      yb[(quad * 4 + rr) * 256 + ii] = (_Float16)acy0[rr];
      yb[(16 + quad * 4 + rr) * 256 + ii] = (_Float16)acy1[rr];
    }
  }
  __syncthreads();  // csum atomics complete
  if (t < 32) csum_ws[b * 32 + t] = csumsh[t];
}

// ---------------------------------------------------------------------------
// k2: grid 256 = 32 j x 8 chunks of 32 batches, block 512 (8 waves).
// s-GEMM: m=batch, n=d, k=c (A from LDS y, B = W16 rows from L2).
// u-GEMM: m=batch, n=c, k=d (A from LDS v, B = WT16 rows from L2).
// ---------------------------------------------------------------------------
__global__ __launch_bounds__(512) void k2(
    const _Float16* __restrict__ W16,   // [j][d][c]
    const _Float16* __restrict__ WT16,  // [j][c][d]
    const float* __restrict__ bias,     // [j*64+d]
    const _Float16* __restrict__ y16,   // [b][j][c]
    const float* __restrict__ csum_ws,  // [b][j]
    _Float16* __restrict__ u16,         // [b][j][c]
    float* __restrict__ vb_ws,          // [b][j]
    float* __restrict__ vout,           // [b][j][d]
    int final_iter)
{
  __shared__ __align__(16) _Float16 ysh[32 * 264];
  __shared__ __align__(16) _Float16 vsh[32 * 72];
  __shared__ float n2sh[32];
  __shared__ float vbsh[32];
  __shared__ float csums[32];

  const int jb = blockIdx.x & 31;
  const int b0 = (blockIdx.x >> 5) * 32;
  const int t = threadIdx.x;
  const int w = t >> 6, lane = t & 63, l15 = lane & 15, quad = lane >> 4;

  // stage y rows for 32 batches (1024 f16x8 / 512 thr = 2 each)
  #pragma unroll
  for (int p0 = 0; p0 < 2; ++p0) {
    const int p = p0 * 512 + t;
    const int bs = p >> 5, co = (p & 31) * 8;
    *reinterpret_cast<f16x8*>(&ysh[bs * 264 + co]) =
        *reinterpret_cast<const f16x8*>(
            &y16[(size_t)(b0 + bs) * 8192 + jb * 256 + co]);
  }
  if (t < 32) {
    csums[t] = csum_ws[(b0 + t) * 32 + jb];
    n2sh[t] = 0.f;
    vbsh[t] = 0.f;
  }
  __syncthreads();

  // ---- s-GEMM: wave w -> (mt = w&1, nt = w>>1) ----
  const int mt = w & 1, nt = w >> 1;
  const _Float16* Wg = W16 + (size_t)jb * 16384;
  f32x4 sacc = (f32x4){0.f, 0.f, 0.f, 0.f};
  #pragma unroll
  for (int kt = 0; kt < 8; ++kt) {
    const int ko = kt * 32 + quad * 8;
    f16x8 a = *reinterpret_cast<const f16x8*>(&ysh[(mt * 16 + l15) * 264 + ko]);
    f16x8 bf = *reinterpret_cast<const f16x8*>(&Wg[(nt * 16 + l15) * 256 + ko]);
    sacc = __builtin_amdgcn_mfma_f32_16x16x32_f16(a, bf, sacc, 0, 0, 0);
  }
  const int d = nt * 16 + l15;
  const float biasd = bias[jb * 64 + d];
  float sv[4];
  #pragma unroll
  for (int rr = 0; rr < 4; ++rr)
    sv[rr] = sacc[rr] + biasd * csums[mt * 16 + quad * 4 + rr];

  // ||s||^2 per batch: l15-shfl reduce then LDS atomic across nt waves
  #pragma unroll
  for (int rr = 0; rr < 4; ++rr) {
    float p = sv[rr] * sv[rr];
    p += __shfl_xor(p, 1);
    p += __shfl_xor(p, 2);
    p += __shfl_xor(p, 4);
    p += __shfl_xor(p, 8);
    if (l15 == 0) atomicAdd(&n2sh[mt * 16 + quad * 4 + rr], p);
  }
  __syncthreads();

  float vv[4];
  #pragma unroll
  for (int rr = 0; rr < 4; ++rr) {
    const float n2 = n2sh[mt * 16 + quad * 4 + rr];
    const float sc = sqrtf(n2) / (1.f + n2);
    vv[rr] = sv[rr] * sc;
  }

  if (final_iter) {
    #pragma unroll
    for (int rr = 0; rr < 4; ++rr)
      vout[((size_t)(b0 + mt * 16 + quad * 4 + rr) * 32 + jb) * 64 + d] = vv[rr];
  } else {
    #pragma unroll
    for (int rr = 0; rr < 4; ++rr) {
      vsh[(mt * 16 + quad * 4 + rr) * 72 + d] = (_Float16)vv[rr];
      float p = vv[rr] * biasd;
      p += __shfl_xor(p, 1);
      p += __shfl_xor(p, 2);
      p += __shfl_xor(p, 4);
      p += __shfl_xor(p, 8);
      if (l15 == 0) atomicAdd(&vbsh[mt * 16 + quad * 4 + rr], p);
    }
    __syncthreads();
    if (t < 32) vb_ws[(b0 + t) * 32 + jb] = vbsh[t];

    // ---- u-GEMM: wave w -> (mt, nt = (w>>1)*4 + q) ----
    const _Float16* WTg = WT16 + (size_t)jb * 16384;
    #pragma unroll
    for (int q = 0; q < 4; ++q) {
      const int ntu = (w >> 1) * 4 + q;
      f32x4 ua = (f32x4){0.f, 0.f, 0.f, 0.f};
      #pragma unroll
      for (int kt = 0; kt < 2; ++kt) {
        const int ko = kt * 32 + quad * 8;
        f16x8 a = *reinterpret_cast<const f16x8*>(&vsh[(mt * 16 + l15) * 72 + ko]);
        f16x8 bf = *reinterpret_cast<const f16x8*>(&WTg[(ntu * 16 + l15) * 64 + ko]);
        ua = __builtin_amdgcn_mfma_f32_16x16x32_f16(a, bf, ua, 0, 0, 0);
      }
      #pragma unroll
      for (int rr = 0; rr < 4; ++rr)
        u16[(size_t)(b0 + mt * 16 + quad * 4 + rr) * 8192 + jb * 256 +
            ntu * 16 + l15] = (_Float16)ua[rr];
    }
  }
}

// ---------------------------------------------------------------------------
extern "C" void kernel_launch(void* const* d_in, const int* in_sizes, int n_in,
                              void* d_out, int out_size, void* d_ws, size_t ws_size,
                              hipStream_t stream) {
  (void)in_sizes; (void)n_in; (void)out_size; (void)ws_size;
  const float* x      = (const float*)d_in[0];
  const float* W      = (const float*)d_in[1];
  const float* bias   = (const float*)d_in[2];
  const float* b_init = (const float*)d_in[3];
  char* ws = (char*)d_ws;

  _Float16* x16  = (_Float16*)(ws);                             // 32 MiB
  _Float16* xT16 = (_Float16*)(ws + (32u << 20));               // 32 MiB
  _Float16* W16  = (_Float16*)(ws + (64u << 20));               // 1 MiB
  _Float16* WT16 = (_Float16*)(ws + (65u << 20));               // 1 MiB
  _Float16* y16  = (_Float16*)(ws + (66u << 20));               // 4 MiB
  _Float16* u16  = (_Float16*)(ws + (70u << 20));               // 4 MiB
  float*    b_ws = (float*)(ws + (74u << 20));                  // 8 MiB
  float*    csum = (float*)(ws + (82u << 20));                  // 32 KiB
  float*    vbws = (float*)(ws + (82u << 20) + (64u << 10));    // 32 KiB
  float*    vout = (float*)d_out;

  prep_x<<<dim3(BSZ, 8), 256, 0, stream>>>(x, x16, xT16);
  prep_w<<<32, 256, 0, stream>>>(W, W16, WT16);

  // iter 1 (mode 0: softmax from b_init)
  k31<<<BSZ, 1024, 0, stream>>>(x16, xT16, u16, vbws, b_init, b_ws, y16, csum, 0);
  k2<<<256, 512, 0, stream>>>(W16, WT16, bias, y16, csum, u16, vbws, vout, 0);
  // iter 2 (mode 1: delta from u0 on b_init, store b1)
  k31<<<BSZ, 1024, 0, stream>>>(x16, xT16, u16, vbws, b_init, b_ws, y16, csum, 1);
  k2<<<256, 512, 0, stream>>>(W16, WT16, bias, y16, csum, u16, vbws, vout, 0);
  // iter 3 (mode 2: delta from u1 on b1, no store)
  k31<<<BSZ, 1024, 0, stream>>>(x16, xT16, u16, vbws, b_ws, b_ws, y16, csum, 2);
  k2<<<256, 512, 0, stream>>>(W16, WT16, bias, y16, csum, u16, vbws, vout, 1);
}

// Round 12
// 190.010 us; speedup vs baseline: 1.3586x; 1.0167x over previous
//
#include <hip/hip_runtime.h>

// CapsNet dynamic routing — split-phase, 7 launches, frag-ordered layouts.
// All intermediate tensors stored in MFMA B-fragment order
// [k-tile][row][quad][8] so every GEMM B-load is 16B/lane, 1KB/wave
// contiguous (no 512-B-stride scatter).
//   prep_w: W fp32 -> Wy (s-GEMM frag order), WTd (u-GEMM frag order)
//   k31 (block=batch, 1024 thr):
//     mode 0: convert x -> x16y + xTd (frag order, global), softmax(b_init), y
//     mode 1: delta = u0@xT, b = b_init + D0 + vb0, softmax, y
//     mode 2: b = b_init + D0+vb0 + D1+vb1 (two MFMA passes), softmax, y
//     (b never stored to global; iter3 recomputes from b_init)
//   k2 (block=(j, 32 batches), 512 thr): s-GEMM (MFMA) + bias*csum, squash,
//     u-GEMM (MFMA) -> u16a/u16b, or vout at final. W read once per 32 b.

#define BSZ 256

typedef _Float16 f16x8 __attribute__((ext_vector_type(8)));
typedef _Float16 f16x4 __attribute__((ext_vector_type(4)));
typedef float f32x4 __attribute__((ext_vector_type(4)));

// ---------------------------------------------------------------------------
// prep_w: grid 32 (block=j), block 256.
// Wy  f16x8 idx (per j, 2048 vecs): kt*256 + d*4 + quad   (kt=c>>5, e=c&7)
// WTd f16x8 idx (per j, 2048 vecs): kt*1024 + cc*4 + quad (kt=d>>5, e=d&7)
// ---------------------------------------------------------------------------
__global__ __launch_bounds__(256) void prep_w(
    const float* __restrict__ W,     // [32*64][256]
    _Float16* __restrict__ Wy,
    _Float16* __restrict__ WTd)
{
  __shared__ __align__(16) float Wsh[64 * 260];
  const int j = blockIdx.x, t = threadIdx.x;

  #pragma unroll
  for (int k = 0; k < 16; ++k) {
    const int q = k * 256 + t;
    const int row = q >> 6, c4 = (q & 63) * 4;
    *reinterpret_cast<f32x4*>(&Wsh[row * 260 + c4]) =
        *reinterpret_cast<const f32x4*>(&W[((size_t)j * 64 + row) * 256 + c4]);
  }
  __syncthreads();

  // Wy: thread t -> (d = t&63, quad = t>>6); 8 kt's
  {
    const int d = t & 63, quad = t >> 6;
    f16x8* out = reinterpret_cast<f16x8*>(Wy) + (size_t)j * 2048;
    #pragma unroll
    for (int kt = 0; kt < 8; ++kt) {
      const int c0 = kt * 32 + quad * 8;
      f16x8 h;
      #pragma unroll
      for (int e = 0; e < 8; ++e) h[e] = (_Float16)Wsh[d * 260 + c0 + e];
      out[kt * 256 + d * 4 + quad] = h;
    }
  }
  // WTd: thread t = cc; 8 (kt,quad) combos
  {
    const int cc = t;
    f16x8* out = reinterpret_cast<f16x8*>(WTd) + (size_t)j * 2048;
    #pragma unroll
    for (int h8 = 0; h8 < 8; ++h8) {
      const int kt = h8 >> 2, quad = h8 & 3;
      f16x8 h;
      #pragma unroll
      for (int e = 0; e < 8; ++e)
        h[e] = (_Float16)Wsh[(h8 * 8 + e) * 260 + cc];
      out[kt * 1024 + cc * 4 + quad] = h;
    }
  }
}

// ---------------------------------------------------------------------------
// k31: grid BSZ, block 1024 (16 waves; wave w owns column w*16+l15).
// x16y f16x8 idx (per b, 8192): kk*1024 + c*4 + quad   (kk=i>>5, e=i&7)
// xTd  f16x8 idx (per b, 8192): kk*1024 + i*4 + quad   (kk=c>>5, e=c&7)
// ---------------------------------------------------------------------------
__global__ __launch_bounds__(1024) void k31(
    const float* __restrict__ x,        // [b][c][i] fp32 (mode 0 only)
    _Float16* __restrict__ x16y,        // frag-ordered
    _Float16* __restrict__ xTd,         // frag-ordered
    const _Float16* __restrict__ u16a,  // [b][j][c]
    const _Float16* __restrict__ u16b,  // [b][j][c]
    const float* __restrict__ vb0,      // [b][j]
    const float* __restrict__ vb1,      // [b][j]
    const float* __restrict__ bsrc,     // [b][j][i] = b_init
    _Float16* __restrict__ y16,         // [b][j][c]
    float* __restrict__ csum_ws,        // [b][j]
    int mode)                            // #u's to apply (0,1,2)
{
  __shared__ __align__(16) _Float16 cs[32 * 264];    // softmax out / y A-frags
  __shared__ __align__(16) _Float16 ushA[32 * 264];  // u0 (delta) then y-repack
  __shared__ __align__(16) _Float16 ushB[32 * 264];  // u1 (mode 2)
  __shared__ float vbs[32];
  __shared__ float csumsh[32];

  const int b = blockIdx.x, t = threadIdx.x;
  const int w = t >> 6, lane = t & 63, l15 = lane & 15, quad = lane >> 4;
  const int ii = w * 16 + l15;
  const float* bp = bsrc + (size_t)b * 8192;

  float breg[2][4];

  if (mode == 0) {
    // ---- convert own x batch: fp32 [c][i] -> x16y + xTd (frag order) ----
    const float* xb = x + (size_t)b * 65536;
    f16x8* xy8 = reinterpret_cast<f16x8*>(x16y) + (size_t)b * 8192;
    _Float16* xtd = xTd + (size_t)b * 65536;
    #pragma unroll
    for (int q = 0; q < 2; ++q) {
      const int p = q * 1024 + t;
      const int i8 = (p & 31) * 8;
      const int c4 = (p >> 5) * 4;
      const int kk = i8 >> 5, qd = (i8 >> 3) & 3;
      const int ktc = c4 >> 5, qdc = (c4 >> 3) & 3, ce = c4 & 7;
      f32x4 v[4][2];
      #pragma unroll
      for (int s = 0; s < 4; ++s) {
        v[s][0] = *reinterpret_cast<const f32x4*>(&xb[(c4 + s) * 256 + i8]);
        v[s][1] = *reinterpret_cast<const f32x4*>(&xb[(c4 + s) * 256 + i8 + 4]);
      }
      #pragma unroll
      for (int s = 0; s < 4; ++s) {
        f16x8 h;
        #pragma unroll
        for (int e = 0; e < 4; ++e) { h[e] = (_Float16)v[s][0][e]; h[4 + e] = (_Float16)v[s][1][e]; }
        xy8[kk * 1024 + (c4 + s) * 4 + qd] = h;
      }
      #pragma unroll
      for (int m = 0; m < 8; ++m) {
        f16x4 h;
        #pragma unroll
        for (int s = 0; s < 4; ++s) h[s] = (_Float16)v[s][m >> 2][m & 3];
        *reinterpret_cast<f16x4*>(
            &xtd[(ktc * 1024 + (i8 + m) * 4 + qdc) * 8 + ce]) = h;
      }
    }
    __syncthreads();  // conversions visible to own block (y-GEMM reads x16y)
    #pragma unroll
    for (int mt = 0; mt < 2; ++mt)
      #pragma unroll
      for (int rr = 0; rr < 4; ++rr)
        breg[mt][rr] = bp[(mt * 16 + quad * 4 + rr) * 256 + ii];
  } else {
    // ---- stage u0 (and u1) -> LDS; combined vb ----
    {
      const f16x8* ug = reinterpret_cast<const f16x8*>(u16a + (size_t)b * 8192);
      const int jr = t >> 5, co = (t & 31) * 8;
      *reinterpret_cast<f16x8*>(&ushA[jr * 264 + co]) = ug[t];
      if (mode == 2) {
        const f16x8* ug2 = reinterpret_cast<const f16x8*>(u16b + (size_t)b * 8192);
        *reinterpret_cast<f16x8*>(&ushB[jr * 264 + co]) = ug2[t];
      }
    }
    if (t < 32) {
      float vv = vb0[b * 32 + t];
      if (mode == 2) vv += vb1[b * 32 + t];
      vbs[t] = vv;
    }
    __syncthreads();

    const f16x8* xT8 = reinterpret_cast<const f16x8*>(xTd) + (size_t)b * 8192;
    f32x4 acc0 = (f32x4){0.f, 0.f, 0.f, 0.f};
    f32x4 acc1 = (f32x4){0.f, 0.f, 0.f, 0.f};
    #pragma unroll
    for (int kk = 0; kk < 8; ++kk) {
      const int ko = kk * 32 + quad * 8;
      f16x8 bf = xT8[kk * 1024 + ii * 4 + quad];   // coalesced 1KB/wave
      f16x8 a0 = *reinterpret_cast<const f16x8*>(&ushA[l15 * 264 + ko]);
      f16x8 a1 = *reinterpret_cast<const f16x8*>(&ushA[(16 + l15) * 264 + ko]);
      acc0 = __builtin_amdgcn_mfma_f32_16x16x32_f16(a0, bf, acc0, 0, 0, 0);
      acc1 = __builtin_amdgcn_mfma_f32_16x16x32_f16(a1, bf, acc1, 0, 0, 0);
      if (mode == 2) {
        f16x8 a2 = *reinterpret_cast<const f16x8*>(&ushB[l15 * 264 + ko]);
        f16x8 a3 = *reinterpret_cast<const f16x8*>(&ushB[(16 + l15) * 264 + ko]);
        acc0 = __builtin_amdgcn_mfma_f32_16x16x32_f16(a2, bf, acc0, 0, 0, 0);
        acc1 = __builtin_amdgcn_mfma_f32_16x16x32_f16(a3, bf, acc1, 0, 0, 0);
      }
    }
    #pragma unroll
    for (int rr = 0; rr < 4; ++rr) {
      const int j0 = quad * 4 + rr, j1 = 16 + quad * 4 + rr;
      breg[0][rr] = bp[j0 * 256 + ii] + acc0[rr] + vbs[j0];
      breg[1][rr] = bp[j1 * 256 + ii] + acc1[rr] + vbs[j1];
    }
  }

  if (t < 32) csumsh[t] = 0.f;

  // ---- softmax over j (registers + shfl across quads/halves) ----
  float cc[2][4];
  {
    float m = breg[0][0];
    #pragma unroll
    for (int mt = 0; mt < 2; ++mt)
      #pragma unroll
      for (int rr = 0; rr < 4; ++rr) m = fmaxf(m, breg[mt][rr]);
    m = fmaxf(m, __shfl_xor(m, 16));
    m = fmaxf(m, __shfl_xor(m, 32));
    float s = 0.f;
    #pragma unroll
    for (int mt = 0; mt < 2; ++mt)
      #pragma unroll
      for (int rr = 0; rr < 4; ++rr) {
        float e = __expf(breg[mt][rr] - m);
        cc[mt][rr] = e; s += e;
      }
    s += __shfl_xor(s, 16);
    s += __shfl_xor(s, 32);
    const float rinv = 1.f / s;
    #pragma unroll
    for (int mt = 0; mt < 2; ++mt)
      #pragma unroll
      for (int rr = 0; rr < 4; ++rr) {
        const float cv = cc[mt][rr] * rinv;
        cc[mt][rr] = cv;
        cs[(mt * 16 + quad * 4 + rr) * 264 + ii] = (_Float16)cv;
      }
  }
  __syncthreads();  // cs visible; csumsh zeroed; ush delta-reads done

  // csum[j]
  #pragma unroll
  for (int mt = 0; mt < 2; ++mt)
    #pragma unroll
    for (int rr = 0; rr < 4; ++rr) {
      float pj = cc[mt][rr];
      pj += __shfl_xor(pj, 1);
      pj += __shfl_xor(pj, 2);
      pj += __shfl_xor(pj, 4);
      pj += __shfl_xor(pj, 8);
      if (l15 == 0) atomicAdd(&csumsh[mt * 16 + quad * 4 + rr], pj);
    }

  // ---- y[j,c] = sum_i c[j,i] * x[c,i]  (B coalesced from x16y) ----
  {
    const f16x8* xy8 = reinterpret_cast<const f16x8*>(x16y) + (size_t)b * 8192;
    f32x4 acy0 = (f32x4){0.f, 0.f, 0.f, 0.f};
    f32x4 acy1 = (f32x4){0.f, 0.f, 0.f, 0.f};
    #pragma unroll
    for (int kk = 0; kk < 8; ++kk) {
      const int ko = kk * 32 + quad * 8;
      f16x8 bf = xy8[kk * 1024 + ii * 4 + quad];
      f16x8 a0 = *reinterpret_cast<const f16x8*>(&cs[l15 * 264 + ko]);
      f16x8 a1 = *reinterpret_cast<const f16x8*>(&cs[(16 + l15) * 264 + ko]);
      acy0 = __builtin_amdgcn_mfma_f32_16x16x32_f16(a0, bf, acy0, 0, 0, 0);
      acy1 = __builtin_amdgcn_mfma_f32_16x16x32_f16(a1, bf, acy1, 0, 0, 0);
    }
    // repack D-layout -> LDS (ushA free now) -> coalesced f16x8 stores
    #pragma unroll
    for (int rr = 0; rr < 4; ++rr) {
      ushA[(quad * 4 + rr) * 264 + ii] = (_Float16)acy0[rr];
      ushA[(16 + quad * 4 + rr) * 264 + ii] = (_Float16)acy1[rr];
    }
  }
  __syncthreads();
  {
    const int jr = t >> 5, co = (t & 31) * 8;
    *reinterpret_cast<f16x8*>(&y16[(size_t)b * 8192 + jr * 256 + co]) =
        *reinterpret_cast<const f16x8*>(&ushA[jr * 264 + co]);
  }
  if (t < 32) csum_ws[b * 32 + t] = csumsh[t];
}

// ---------------------------------------------------------------------------
// k2: grid 256 = 32 j x 8 chunks of 32 batches, block 512 (8 waves).
// ---------------------------------------------------------------------------
__global__ __launch_bounds__(512) void k2(
    const _Float16* __restrict__ Wy,
    const _Float16* __restrict__ WTd,
    const float* __restrict__ bias,
    const _Float16* __restrict__ y16,   // [b][j][c]
    const float* __restrict__ csum_ws,  // [b][j]
    _Float16* __restrict__ u16,         // [b][j][c] (target buffer)
    float* __restrict__ vb_ws,          // [b][j]
    float* __restrict__ vout,           // [b][j][d]
    int final_iter)
{
  __shared__ __align__(16) _Float16 ysh[32 * 264];   // y stage, then u-repack
  __shared__ __align__(16) _Float16 vsh[32 * 72];
  __shared__ float n2sh[32];
  __shared__ float vbsh[32];
  __shared__ float csums[32];

  const int jb = blockIdx.x & 31;
  const int b0 = (blockIdx.x >> 5) * 32;
  const int t = threadIdx.x;
  const int w = t >> 6, lane = t & 63, l15 = lane & 15, quad = lane >> 4;

  #pragma unroll
  for (int p0 = 0; p0 < 2; ++p0) {
    const int p = p0 * 512 + t;
    const int bs = p >> 5, co = (p & 31) * 8;
    *reinterpret_cast<f16x8*>(&ysh[bs * 264 + co]) =
        *reinterpret_cast<const f16x8*>(
            &y16[(size_t)(b0 + bs) * 8192 + jb * 256 + co]);
  }
  if (t < 32) {
    csums[t] = csum_ws[(b0 + t) * 32 + jb];
    n2sh[t] = 0.f;
    vbsh[t] = 0.f;
  }
  __syncthreads();

  // ---- s-GEMM: wave w -> (mt = w&1, nt = w>>1) ----
  const int mt = w & 1, nt = w >> 1;
  const f16x8* Wg8 = reinterpret_cast<const f16x8*>(Wy) + (size_t)jb * 2048;
  const int d = nt * 16 + l15;
  f32x4 sacc = (f32x4){0.f, 0.f, 0.f, 0.f};
  #pragma unroll
  for (int kt = 0; kt < 8; ++kt) {
    const int ko = kt * 32 + quad * 8;
    f16x8 a = *reinterpret_cast<const f16x8*>(&ysh[(mt * 16 + l15) * 264 + ko]);
    f16x8 bf = Wg8[kt * 256 + d * 4 + quad];   // coalesced
    sacc = __builtin_amdgcn_mfma_f32_16x16x32_f16(a, bf, sacc, 0, 0, 0);
  }
  const float biasd = bias[jb * 64 + d];
  float sv[4];
  #pragma unroll
  for (int rr = 0; rr < 4; ++rr)
    sv[rr] = sacc[rr] + biasd * csums[mt * 16 + quad * 4 + rr];

  #pragma unroll
  for (int rr = 0; rr < 4; ++rr) {
    float p = sv[rr] * sv[rr];
    p += __shfl_xor(p, 1);
    p += __shfl_xor(p, 2);
    p += __shfl_xor(p, 4);
    p += __shfl_xor(p, 8);
    if (l15 == 0) atomicAdd(&n2sh[mt * 16 + quad * 4 + rr], p);
  }
  __syncthreads();

  float vv[4];
  #pragma unroll
  for (int rr = 0; rr < 4; ++rr) {
    const float n2 = n2sh[mt * 16 + quad * 4 + rr];
    const float sc = sqrtf(n2) / (1.f + n2);
    vv[rr] = sv[rr] * sc;
  }

  if (final_iter) {
    #pragma unroll
    for (int rr = 0; rr < 4; ++rr)
      vout[((size_t)(b0 + mt * 16 + quad * 4 + rr) * 32 + jb) * 64 + d] = vv[rr];
  } else {
    #pragma unroll
    for (int rr = 0; rr < 4; ++rr) {
      vsh[(mt * 16 + quad * 4 + rr) * 72 + d] = (_Float16)vv[rr];
      float p = vv[rr] * biasd;
      p += __shfl_xor(p, 1);
      p += __shfl_xor(p, 2);
      p += __shfl_xor(p, 4);
      p += __shfl_xor(p, 8);
      if (l15 == 0) atomicAdd(&vbsh[mt * 16 + quad * 4 + rr], p);
    }
    __syncthreads();   // vsh complete; ysh reads done -> reuse as u-repack
    if (t < 32) vb_ws[(b0 + t) * 32 + jb] = vbsh[t];

    // ---- u-GEMM: wave w -> (mt, ntu = (w>>1)*4 + q) ----
    const f16x8* WT8 = reinterpret_cast<const f16x8*>(WTd) + (size_t)jb * 2048;
    #pragma unroll
    for (int q = 0; q < 4; ++q) {
      const int ntu = (w >> 1) * 4 + q;
      const int cc = ntu * 16 + l15;
      f32x4 ua = (f32x4){0.f, 0.f, 0.f, 0.f};
      #pragma unroll
      for (int kt = 0; kt < 2; ++kt) {
        const int ko = kt * 32 + quad * 8;
        f16x8 a = *reinterpret_cast<const f16x8*>(&vsh[(mt * 16 + l15) * 72 + ko]);
        f16x8 bf = WT8[kt * 1024 + cc * 4 + quad];   // coalesced
        ua = __builtin_amdgcn_mfma_f32_16x16x32_f16(a, bf, ua, 0, 0, 0);
      }
      #pragma unroll
      for (int rr = 0; rr < 4; ++rr)
        ysh[(mt * 16 + quad * 4 + rr) * 264 + cc] = (_Float16)ua[rr];
    }
    __syncthreads();
    // coalesced u16 write-out
    #pragma unroll
    for (int p0 = 0; p0 < 2; ++p0) {
      const int p = p0 * 512 + t;
      const int bs = p >> 5, co = (p & 31) * 8;
      *reinterpret_cast<f16x8*>(&u16[(size_t)(b0 + bs) * 8192 + jb * 256 + co]) =
          *reinterpret_cast<const f16x8*>(&ysh[bs * 264 + co]);
    }
  }
}

// ---------------------------------------------------------------------------
extern "C" void kernel_launch(void* const* d_in, const int* in_sizes, int n_in,
                              void* d_out, int out_size, void* d_ws, size_t ws_size,
                              hipStream_t stream) {
  (void)in_sizes; (void)n_in; (void)out_size; (void)ws_size;
  const float* x      = (const float*)d_in[0];
  const float* W      = (const float*)d_in[1];
  const float* bias   = (const float*)d_in[2];
  const float* b_init = (const float*)d_in[3];
  char* ws = (char*)d_ws;

  _Float16* x16y = (_Float16*)(ws);                             // 32 MiB
  _Float16* xTd  = (_Float16*)(ws + (32u << 20));               // 32 MiB
  _Float16* Wy   = (_Float16*)(ws + (64u << 20));               // 1 MiB
  _Float16* WTd  = (_Float16*)(ws + (65u << 20));               // 1 MiB
  _Float16* y16  = (_Float16*)(ws + (66u << 20));               // 4 MiB
  _Float16* u16a = (_Float16*)(ws + (70u << 20));               // 4 MiB
  _Float16* u16b = (_Float16*)(ws + (74u << 20));               // 4 MiB
  float*    csum = (float*)(ws + (78u << 20));                  // 32 KiB
  float*    vb0  = (float*)(ws + (78u << 20) + (64u << 10));    // 32 KiB
  float*    vb1  = (float*)(ws + (78u << 20) + (128u << 10));   // 32 KiB
  float*    vout = (float*)d_out;

  prep_w<<<32, 256, 0, stream>>>(W, Wy, WTd);
  // iter 1: convert + softmax(b_init) + y
  k31<<<BSZ, 1024, 0, stream>>>(x, x16y, xTd, u16a, u16b, vb0, vb1, b_init,
                                y16, csum, 0);
  k2<<<256, 512, 0, stream>>>(Wy, WTd, bias, y16, csum, u16a, vb0, vout, 0);
  // iter 2: b = b_init + D(u0)+vb0
  k31<<<BSZ, 1024, 0, stream>>>(x, x16y, xTd, u16a, u16b, vb0, vb1, b_init,
                                y16, csum, 1);
  k2<<<256, 512, 0, stream>>>(Wy, WTd, bias, y16, csum, u16b, vb1, vout, 0);
  // iter 3: b = b_init + D(u0)+vb0 + D(u1)+vb1
  k31<<<BSZ, 1024, 0, stream>>>(x, x16y, xTd, u16a, u16b, vb0, vb1, b_init,
                                y16, csum, 2);
  k2<<<256, 512, 0, stream>>>(Wy, WTd, bias, y16, csum, u16a, vb0, vout, 1);
}